// Round 11
// baseline (45.135 us; speedup 1.0000x reference)
//
#include <hip/hip_runtime.h>
#include <cstdint>
#include <cstddef>

#define LOG2E 1.4426950408889634f

// ---- DPP cross-lane add: v += v[permuted lane] (pure VALU, no LDS pipe) ----
template<int CTRL>
__device__ __forceinline__ float dpp_addf(float v) {
  const int s = __builtin_amdgcn_update_dpp(
      0, __builtin_bit_cast(int, v), CTRL, 0xF, 0xF, true);
  return v + __builtin_bit_cast(float, s);
}
#define DPP_XOR1     0xB1   // quad_perm [1,0,3,2]
#define DPP_XOR2     0x4E   // quad_perm [2,3,0,1]
#define DPP_HALF_MIR 0x141  // 8-lane mirror (completes 8-group after XOR1,2)
#define DPP_ROW_MIR  0x140  // 16-lane mirror (completes 16-group)

// lane-broadcast via VALU: reads lane 'l' (imm) of v into an SGPR at use site
__device__ __forceinline__ float rlane(float v, int l) {
  return __builtin_bit_cast(float,
      __builtin_amdgcn_readlane(__builtin_bit_cast(int, v), l));
}

// async global->LDS: HW writes wave-uniform LDS base + lane*16B (vmcnt)
__device__ __forceinline__ void gld_lds16(const float* g, float* l) {
  __builtin_amdgcn_global_load_lds(
      (const __attribute__((address_space(1))) void*)g,
      (__attribute__((address_space(3))) void*)l, 16, 0, 0);
}

// involution swizzle on 16B-block index: frag reads land 8 lanes/bank-quad
__device__ __forceinline__ int swz(int b) { return b ^ ((b >> 3) & 7); }

// stage one 16KB half (512 rows x 8 k), 4-wave block: LDS[blk]=G[swz(blk)]
__device__ __forceinline__ void stage_half(const float* Wg, float* buf,
                                           int wv, int ln) {
  #pragma unroll
  for (int t = 0; t < 4; ++t) {
    const int seg = ((wv << 2) + t) << 8;      // wave-uniform dest word base
    const int j   = swz((seg >> 2) + ln);      // source 16B-block for this slot
    gld_lds16(Wg + ((j >> 1) << 4) + ((j & 1) << 2), buf + seg);
  }
}

// full 32KB W tile for one i: k 0..7 -> buf[0..4095], k 8..15 -> buf[4096..]
__device__ __forceinline__ void stage_tile(const float* WtI, float* buf,
                                           int wv, int ln) {
  stage_half(WtI,     buf,        wv, ln);
  stage_half(WtI + 8, buf + 4096, wv, ln);
}

// this block's 16 b's x 16 k for one i -> 256 floats LDS linear [b][k]; wave 0
__device__ __forceinline__ void stage_x(const float* Xi, float* dst, int tid) {
  if (tid < 64) {
    gld_lds16(Xi + ((size_t)(tid >> 2) << 15) + ((tid & 3) << 2), dst);
  }
}

// barrier waiting LDS ops only; async staging (vmcnt) stays in flight (T4)
__device__ __forceinline__ void lds_barrier() {
  asm volatile("s_waitcnt lgkmcnt(0)\n\ts_barrier" ::: "memory");
}

// K1: grid 1024 (g = bid&511 picks 4 i's; h = bid>>9 picks the 16-b half),
// block 256 thr (4 waves). Rounds 8-10 showed the wall (≈23.6k cyc/ii) is
// ~2x the sum of VALU+LDS busy time and insensitive to instruction mix ->
// lockstep barrier skew over the 8-wave domain + only 2 independent blocks/CU.
// This round halves the barrier domain (4 waves) and doubles block-level TLP:
// LDS 39.9KB (no pad) and VGPR ~68 both give 4 blocks/CU -> 4 independent
// 4-wave pipelines per CU filling each other's bubbles.
// Per-thread code and ALL summation orders are unchanged (bit-identical).
// W is fetched twice (h=0 grid-half first; h=1 re-read hits L3: W=67MB<256MB).
// part layout unchanged: both h-halves of slab g write disjoint b-ranges ->
// K2 is byte-identical to previous rounds.
template<bool ATOMIC>
__global__ __launch_bounds__(256)
void caps_main(const float* __restrict__ X, const float* __restrict__ Wt,
               float* __restrict__ part) {
  __shared__ float sW[8192];        // 32 KB: single W tile (deep prefetch)
  __shared__ float sX[2][256];      // 2 KB: double-buffered x tiles (16 b)
  __shared__ float sWs[32 * 20];    // d-summed W (2.5 KB)
  __shared__ float sC[32 * 20];     // c2[n][b_local] (2.5 KB)
  // total 39.9 KB -> 4 blocks/CU

  const int tid  = threadIdx.x;
  const int wv   = tid >> 6, ln = tid & 63;
  const int g    = blockIdx.x & 511;          // i-group
  const int h    = blockIdx.x >> 9;           // b-half (0: b0-15, 1: b16-31)
  const int i0   = g << 2;

  const float* Xh = X + (((size_t)(h << 4)) << 15);   // this half's x base

  stage_tile(Wt + ((size_t)i0 << 13), sW, wv, ln);
  stage_x(Xh + ((size_t)i0 << 4), sX[0], tid);

  const int bB = tid >> 4;                    // phase-B local batch 0..15
  const int n1 = tid & 15;                    // phase-B n-low
  const int j0 = tid << 2;                    // lane's base 16B-block
  const int nr = tid >> 3;                    // lane's capsule (both rows)

  float acc0[16], acc1[16];
  #pragma unroll
  for (int b = 0; b < 16; ++b) { acc0[b] = 0.f; acc1[b] = 0.f; }

  #pragma clang loop unroll(disable)
  for (int ii = 0; ii < 4; ++ii) {
    const int p = ii & 1;           // runtime parity: address math only
    __syncthreads();                // vmcnt drain: W(ii)+x(ii) staged full
                                    // iteration ago -> wait is ~free

    // ---- phase A: all 8 lane rows -> regs (tile ii) ----
    const float4 wa0 = *(const float4*)&sW[swz(j0 + 0) << 2];
    const float4 wa1 = *(const float4*)&sW[swz(j0 + 1) << 2];
    const float4 wb0 = *(const float4*)&sW[swz(j0 + 2) << 2];
    const float4 wb1 = *(const float4*)&sW[swz(j0 + 3) << 2];
    const float4 wa2 = *(const float4*)&sW[4096 + (swz(j0 + 0) << 2)];
    const float4 wa3 = *(const float4*)&sW[4096 + (swz(j0 + 1) << 2)];
    const float4 wb2 = *(const float4*)&sW[4096 + (swz(j0 + 2) << 2)];
    const float4 wb3 = *(const float4*)&sW[4096 + (swz(j0 + 3) << 2)];

    // pass-2 x, read here so its LDS latency hides under DPP + barrier:
    // lane L holds x[L>>2][4*(L&3) .. 4*(L&3)+3]  (sX linear [b][k])
    const float4 xv = *(const float4*)&sX[p][ln << 2];

    // ---- Ws[n][k]: 8-lane DPP reduce (all 4 waves, full 16 k) ----
    {
      float pr[16] = { wa0.x+wb0.x, wa0.y+wb0.y, wa0.z+wb0.z, wa0.w+wb0.w,
                       wa1.x+wb1.x, wa1.y+wb1.y, wa1.z+wb1.z, wa1.w+wb1.w,
                       wa2.x+wb2.x, wa2.y+wb2.y, wa2.z+wb2.z, wa2.w+wb2.w,
                       wa3.x+wb3.x, wa3.y+wb3.y, wa3.z+wb3.z, wa3.w+wb3.w };
      #pragma unroll
      for (int q = 0; q < 16; ++q) {
        float v = pr[q];
        v = dpp_addf<DPP_XOR1>(v);
        v = dpp_addf<DPP_XOR2>(v);
        v = dpp_addf<DPP_HALF_MIR>(v);
        pr[q] = v;
      }
      if ((tid & 7) < 4) {
        const int m = tid & 3;
        const float4 w =
            (m & 2) ? ((m & 1) ? make_float4(pr[12], pr[13], pr[14], pr[15])
                               : make_float4(pr[8],  pr[9],  pr[10], pr[11]))
                    : ((m & 1) ? make_float4(pr[4],  pr[5],  pr[6],  pr[7])
                               : make_float4(pr[0],  pr[1],  pr[2],  pr[3]));
        *(float4*)&sWs[(tid >> 3) * 20 + (m << 2)] = w;
      }
    }

    lds_barrier();                  // #1: frag/xv reads + sWs writes done ->
                                    // sW free, sWs ready (vmcnt untouched)

    if (ii < 3) {                   // stage next i: full-iteration distance
      stage_x(Xh + ((size_t)(i0 + ii + 1) << 4), sX[p ^ 1], tid);
      stage_tile(Wt + ((size_t)(i0 + ii + 1) << 13), sW, wv, ln);
    }                               // async; drained at next loop-top sync

    // ---- phase B: x from LDS (broadcast) -> 2-round softmax -> sC ----
    {
      const float* xr = &sX[p][bB << 4];
      const float4 x0 = *(const float4*)(xr + 0);
      const float4 x1 = *(const float4*)(xr + 4);
      const float4 x2 = *(const float4*)(xr + 8);
      const float4 x3 = *(const float4*)(xr + 12);
      float t1 = 0.f, t2 = 0.f;
      #pragma unroll
      for (int c4 = 0; c4 < 4; ++c4) {
        const float4 A1 = *(const float4*)&sWs[n1 * 20 + (c4 << 2)];
        const float4 A2 = *(const float4*)&sWs[(n1 + 16) * 20 + (c4 << 2)];
        const float4 xc = (c4 == 0) ? x0 : (c4 == 1) ? x1 : (c4 == 2) ? x2 : x3;
        t1 += A1.x * xc.x + A1.y * xc.y + A1.z * xc.z + A1.w * xc.w;
        t2 += A2.x * xc.x + A2.y * xc.y + A2.z * xc.z + A2.w * xc.w;
      }
      const float l1a = t1 * 0.03125f, l1b = t2 * 0.03125f;   // b1 = t/32
      const float e1a = exp2f(l1a * LOG2E), e1b = exp2f(l1b * LOG2E);
      float s1 = e1a + e1b;
      s1 = dpp_addf<DPP_XOR1>(s1); s1 = dpp_addf<DPP_XOR2>(s1);
      s1 = dpp_addf<DPP_HALF_MIR>(s1); s1 = dpp_addf<DPP_ROW_MIR>(s1);
      const float rs1 = __builtin_amdgcn_rcpf(s1);
      const float l2a = l1a + e1a * rs1 * t1;                 // b2 = b1 + c1*t
      const float l2b = l1b + e1b * rs1 * t2;
      const float e2a = exp2f(l2a * LOG2E), e2b = exp2f(l2b * LOG2E);
      float s2 = e2a + e2b;
      s2 = dpp_addf<DPP_XOR1>(s2); s2 = dpp_addf<DPP_XOR2>(s2);
      s2 = dpp_addf<DPP_HALF_MIR>(s2); s2 = dpp_addf<DPP_ROW_MIR>(s2);
      const float rs2 = __builtin_amdgcn_rcpf(s2);
      sC[n1 * 20 + bB]        = e2a * rs2;
      sC[(n1 + 16) * 20 + bB] = e2b * rs2;
    }

    // ---- u-hoist: steps 0..7 (frags x readlane-x; independent of sC) ----
    float us0[8], us1[8];
    #pragma unroll
    for (int st = 0; st < 8; ++st) {
      if ((st & 3) == 0) __builtin_amdgcn_sched_barrier(0);  // 4-step window
      const int lb = st << 2;                 // lanes lb..lb+3 hold b=st
      const float s00 = rlane(xv.x, lb + 0), s01 = rlane(xv.y, lb + 0),
                  s02 = rlane(xv.z, lb + 0), s03 = rlane(xv.w, lb + 0);
      const float s10 = rlane(xv.x, lb + 1), s11 = rlane(xv.y, lb + 1),
                  s12 = rlane(xv.z, lb + 1), s13 = rlane(xv.w, lb + 1);
      const float s20 = rlane(xv.x, lb + 2), s21 = rlane(xv.y, lb + 2),
                  s22 = rlane(xv.z, lb + 2), s23 = rlane(xv.w, lb + 2);
      const float s30 = rlane(xv.x, lb + 3), s31 = rlane(xv.y, lb + 3),
                  s32 = rlane(xv.z, lb + 3), s33 = rlane(xv.w, lb + 3);
      us0[st] = wa0.x*s00 + wa0.y*s01 + wa0.z*s02 + wa0.w*s03
              + wa1.x*s10 + wa1.y*s11 + wa1.z*s12 + wa1.w*s13
              + wa2.x*s20 + wa2.y*s21 + wa2.z*s22 + wa2.w*s23
              + wa3.x*s30 + wa3.y*s31 + wa3.z*s32 + wa3.w*s33;
      us1[st] = wb0.x*s00 + wb0.y*s01 + wb0.z*s02 + wb0.w*s03
              + wb1.x*s10 + wb1.y*s11 + wb1.z*s12 + wb1.w*s13
              + wb2.x*s20 + wb2.y*s21 + wb2.z*s22 + wb2.w*s23
              + wb3.x*s30 + wb3.y*s31 + wb3.z*s32 + wb3.w*s33;
    }

    lds_barrier();                            // #2: sC ready (vmcnt untouched)

    // ---- pass 2 epilog: c2 weights; fold hoisted steps; finish 8..15 ----
    float c2s[16];
    {
      const int cb = nr * 20;
      *(float4*)&c2s[0]  = *(const float4*)&sC[cb + 0];
      *(float4*)&c2s[4]  = *(const float4*)&sC[cb + 4];
      *(float4*)&c2s[8]  = *(const float4*)&sC[cb + 8];
      *(float4*)&c2s[12] = *(const float4*)&sC[cb + 12];
    }
    #pragma unroll
    for (int st = 0; st < 8; ++st) {
      acc0[st] += c2s[st] * us0[st];
      acc1[st] += c2s[st] * us1[st];
    }
    #pragma unroll
    for (int st = 8; st < 16; ++st) {
      if ((st & 3) == 0) __builtin_amdgcn_sched_barrier(0);  // 4-step window
      const int lb = st << 2;
      const float s00 = rlane(xv.x, lb + 0), s01 = rlane(xv.y, lb + 0),
                  s02 = rlane(xv.z, lb + 0), s03 = rlane(xv.w, lb + 0);
      const float s10 = rlane(xv.x, lb + 1), s11 = rlane(xv.y, lb + 1),
                  s12 = rlane(xv.z, lb + 1), s13 = rlane(xv.w, lb + 1);
      const float s20 = rlane(xv.x, lb + 2), s21 = rlane(xv.y, lb + 2),
                  s22 = rlane(xv.z, lb + 2), s23 = rlane(xv.w, lb + 2);
      const float s30 = rlane(xv.x, lb + 3), s31 = rlane(xv.y, lb + 3),
                  s32 = rlane(xv.z, lb + 3), s33 = rlane(xv.w, lb + 3);
      float u0 = wa0.x*s00 + wa0.y*s01 + wa0.z*s02 + wa0.w*s03
               + wa1.x*s10 + wa1.y*s11 + wa1.z*s12 + wa1.w*s13
               + wa2.x*s20 + wa2.y*s21 + wa2.z*s22 + wa2.w*s23
               + wa3.x*s30 + wa3.y*s31 + wa3.z*s32 + wa3.w*s33;
      float u1 = wb0.x*s00 + wb0.y*s01 + wb0.z*s02 + wb0.w*s03
               + wb1.x*s10 + wb1.y*s11 + wb1.z*s12 + wb1.w*s13
               + wb2.x*s20 + wb2.y*s21 + wb2.z*s22 + wb2.w*s23
               + wb3.x*s30 + wb3.y*s31 + wb3.z*s32 + wb3.w*s33;
      acc0[st] += c2s[st] * u0;
      acc1[st] += c2s[st] * u1;
    }
  }

  if constexpr (ATOMIC) {
    #pragma unroll
    for (int j = 0; j < 16; ++j) {
      const int bgl = (h << 4) + j;
      float* dst = part + ((size_t)bgl << 9) + (tid << 1);
      atomicAdd(dst, acc0[j]);
      atomicAdd(dst + 1, acc1[j]);
    }
  } else {
    float* wp = part + ((size_t)g << 14) + (tid << 1);
    #pragma unroll
    for (int j = 0; j < 16; ++j) {
      const int bgl = (h << 4) + j;
      *(float2*)(wp + ((size_t)bgl << 9)) = make_float2(acc0[j], acc1[j]);
    }
  }
}

// K2: reduce 512 partials + squash. grid 256 (b = bid>>3, r-block = bid&7).
__global__ __launch_bounds__(512)
void caps_reduce(const float* __restrict__ part, float* __restrict__ out) {
  __shared__ float sred[32][64];
  const int tid = threadIdx.x;
  const int bid = blockIdx.x;            // 0..255
  const int b  = bid >> 3;               // 0..31
  const int rb = bid & 7;                // 64-elem row block
  const int pg = tid >> 4;               // 0..31: sums ig in [16pg, 16pg+16)
  const int sl = tid & 15;               // float4 slot
  const float* src = part + (((size_t)pg << 4) << 14)
                   + (b << 9) + (rb << 6) + (sl << 2);
  float4 a = make_float4(0.f, 0.f, 0.f, 0.f);
  #pragma unroll 4
  for (int p = 0; p < 16; ++p) {
    const float4 v = *(const float4*)(src + ((size_t)p << 14));
    a.x += v.x; a.y += v.y; a.z += v.z; a.w += v.w;
  }
  *(float4*)&sred[pg][sl << 2] = a;
  __syncthreads();
  if (tid < 64) {
    float s = 0.f;
    #pragma unroll
    for (int g = 0; g < 32; ++g) s += sred[g][tid];
    float sq = s * s;
    sq += __shfl_xor(sq, 1); sq += __shfl_xor(sq, 2);
    sq += __shfl_xor(sq, 4); sq += __shfl_xor(sq, 8);   // sum over d (16 r's)
    const float scale = sq / (1.0f + sq) / sqrtf(sq + 1e-7f);
    out[(b << 9) + (rb << 6) + tid] = scale * s;
  }
}

// fallback path: squash fully-accumulated sums
__global__ __launch_bounds__(256)
void caps_squash(const float* __restrict__ sums, float* __restrict__ out) {
  const int e = (blockIdx.x << 8) + threadIdx.x;
  const float s = sums[e];
  float sq = s * s;
  sq += __shfl_xor(sq, 1); sq += __shfl_xor(sq, 2);
  sq += __shfl_xor(sq, 4); sq += __shfl_xor(sq, 8);
  const float scale = sq / (1.0f + sq) / sqrtf(sq + 1e-7f);
  out[e] = scale * s;
}

extern "C" void kernel_launch(void* const* d_in, const int* in_sizes, int n_in,
                              void* d_out, int out_size, void* d_ws, size_t ws_size,
                              hipStream_t stream) {
  const float* X  = (const float*)d_in[0];
  const float* Wt = (const float*)d_in[1];
  float* out = (float*)d_out;
  float* wsf = (float*)d_ws;
  const size_t need = (size_t)512 * 16384 * sizeof(float);
  if (ws_size >= need) {
    caps_main<false><<<1024, 256, 0, stream>>>(X, Wt, wsf);
    caps_reduce<<<256, 512, 0, stream>>>(wsf, out);
  } else {
    float* acc = (ws_size >= (size_t)16384 * sizeof(float)) ? wsf : out;
    hipMemsetAsync(acc, 0, 16384 * sizeof(float), stream);
    caps_main<true><<<1024, 256, 0, stream>>>(X, Wt, acc);
    caps_squash<<<64, 256, 0, stream>>>(acc, out);
  }
}

// Round 12
// 44.163 us; speedup vs baseline: 1.0220x; 1.0220x over previous
//
#include <hip/hip_runtime.h>
#include <cstdint>
#include <cstddef>

#define LOG2E 1.4426950408889634f

// ---- DPP cross-lane add: v += v[permuted lane] (pure VALU, no LDS pipe) ----
template<int CTRL>
__device__ __forceinline__ float dpp_addf(float v) {
  const int s = __builtin_amdgcn_update_dpp(
      0, __builtin_bit_cast(int, v), CTRL, 0xF, 0xF, true);
  return v + __builtin_bit_cast(float, s);
}
#define DPP_XOR1     0xB1   // quad_perm [1,0,3,2]
#define DPP_XOR2     0x4E   // quad_perm [2,3,0,1]
#define DPP_HALF_MIR 0x141  // 8-lane mirror (completes 8-group after XOR1,2)
#define DPP_ROW_MIR  0x140  // 16-lane mirror (completes 16-group)

// lane-broadcast via VALU: reads lane 'l' (imm) of v into an SGPR at use site
__device__ __forceinline__ float rlane(float v, int l) {
  return __builtin_bit_cast(float,
      __builtin_amdgcn_readlane(__builtin_bit_cast(int, v), l));
}

// async global->LDS: HW writes wave-uniform LDS base + lane*16B (vmcnt)
__device__ __forceinline__ void gld_lds16(const float* g, float* l) {
  __builtin_amdgcn_global_load_lds(
      (const __attribute__((address_space(1))) void*)g,
      (__attribute__((address_space(3))) void*)l, 16, 0, 0);
}

// involution swizzle on 16B-block index: frag reads land 8 lanes/bank-quad
__device__ __forceinline__ int swz(int b) { return b ^ ((b >> 3) & 7); }

// stage one 16KB half (512 rows x 8 k), 8-wave block: LDS[blk]=G[swz(blk)]
__device__ __forceinline__ void stage_half(const float* Wg, float* buf,
                                           int wv, int ln) {
  #pragma unroll
  for (int t = 0; t < 2; ++t) {
    const int seg = ((wv << 1) + t) << 8;      // wave-uniform dest word base
    const int j   = swz((seg >> 2) + ln);      // source 16B-block for this slot
    gld_lds16(Wg + ((j >> 1) << 4) + ((j & 1) << 2), buf + seg);
  }
}

// full 32KB W tile for one i: k 0..7 -> buf[0..4095], k 8..15 -> buf[4096..]
__device__ __forceinline__ void stage_tile(const float* WtI, float* buf,
                                           int wv, int ln) {
  stage_half(WtI,     buf,        wv, ln);
  stage_half(WtI + 8, buf + 4096, wv, ln);
}

// x[b][0..15] for one i, all 32 b -> 512 words LDS linear [b][k]; waves 0-1.
__device__ __forceinline__ void stage_x(const float* Xi, float* dst, int tid) {
  if (tid < 128) {
    gld_lds16(Xi + ((size_t)(tid >> 2) << 15) + ((tid & 3) << 2),
              dst + ((tid >> 6) << 8));
  }
}

// barrier waiting LDS ops only; async staging (vmcnt) stays in flight (T4)
__device__ __forceinline__ void lds_barrier() {
  asm volatile("s_waitcnt lgkmcnt(0)\n\ts_barrier" ::: "memory");
}

// K1: grid 512 (bg=1: W read once), block 512 thr (8 waves), 4 i's x all 32 b.
//
// Round-12 change -- SINGLE VARIABLE vs round 10 (best-known, main ~39us):
// the sPad occupancy shaper is DELETED. It was tuned for the pre-session
// structure (per-lane global x + s_load chains) to force 2 blocks/CU; the
// current structure (LDS-resident x, one vmcnt drain/ii) never re-tested it.
// LDS drops 53.5KB -> 43KB -> 3 blocks/CU -> 24 waves/CU (+50% TLP; VGPR
// 6 waves/SIMD x 68 = 408 < 512 fits). Rounds 8-11 showed wall time is
// insensitive to instruction mix at fixed 16 waves/CU (VALUBusy 45%, LDS
// ~25%, HBM ~25%, nothing saturated -> latency/sync bubbles). A 3rd
// independent 8-wave pipeline per CU is the first genuine TLP increase of
// the session. Round 11 (same 16 waves, smaller domains, W x2) was neutral
// -> domain size is not the lever; resident-wave count is the hypothesis.
//
// Everything else byte-identical to round 10:
//  - rolled single-sW deep-prefetch loop (unroll was the r1-6 spill poison)
//  - pass-2 x: ONE per-lane ds_read_b128 + v_readlane imm broadcasts,
//    window fence every 4 steps
//  - DPP (register-only) before barrier #1; 3 barriers/ii total
//  - u-hoist of steps 0..7 filling the softmax lockstep bubble
// Summation order UNCHANGED everywhere (bit-identical; absmax stays 0).
template<bool ATOMIC>
__global__ __launch_bounds__(512)
void caps_main(const float* __restrict__ X, const float* __restrict__ Wt,
               float* __restrict__ part) {
  __shared__ float sW[8192];        // 32 KB: single W tile (deep prefetch)
  __shared__ float sX[2][512];      // 4 KB: double-buffered x tiles
  __shared__ float sWs[32 * 20];    // d-summed W (2.5 KB)
  __shared__ float sC[32 * 36];     // c2[n][b] (4.5 KB)
  // total 43 KB -> 3 blocks/CU (no shaper)

  const int tid  = threadIdx.x;
  const int wv   = tid >> 6, ln = tid & 63;
  const int t256 = tid & 255;
  const int bh   = tid >> 8;                  // b-half for pass 2
  const int i0   = blockIdx.x << 2;

  stage_tile(Wt + ((size_t)i0 << 13), sW, wv, ln);
  stage_x(X + ((size_t)i0 << 4), sX[0], tid);

  const int bB = tid >> 4;                    // phase-B batch 0..31
  const int n1 = tid & 15;                    // phase-B n-low
  const int j0 = t256 << 2;                   // lane's base 16B-block
  const int nr = t256 >> 3;                   // lane's capsule (both rows)

  float acc0[16], acc1[16];
  #pragma unroll
  for (int b = 0; b < 16; ++b) { acc0[b] = 0.f; acc1[b] = 0.f; }

  #pragma clang loop unroll(disable)
  for (int ii = 0; ii < 4; ++ii) {
    const int p = ii & 1;           // runtime parity: address math only
    __syncthreads();                // vmcnt drain: W(ii)+x(ii) staged full
                                    // iteration ago -> wait is ~free

    // ---- phase A: all 8 lane rows -> regs (tile ii) ----
    const float4 wa0 = *(const float4*)&sW[swz(j0 + 0) << 2];
    const float4 wa1 = *(const float4*)&sW[swz(j0 + 1) << 2];
    const float4 wb0 = *(const float4*)&sW[swz(j0 + 2) << 2];
    const float4 wb1 = *(const float4*)&sW[swz(j0 + 3) << 2];
    const float4 wa2 = *(const float4*)&sW[4096 + (swz(j0 + 0) << 2)];
    const float4 wa3 = *(const float4*)&sW[4096 + (swz(j0 + 1) << 2)];
    const float4 wb2 = *(const float4*)&sW[4096 + (swz(j0 + 2) << 2)];
    const float4 wb3 = *(const float4*)&sW[4096 + (swz(j0 + 3) << 2)];

    // pass-2 x, read here so its LDS latency hides under DPP + barrier:
    // lane L holds x[bh*16 + (L>>2)][4*(L&3) .. 4*(L&3)+3]
    const float4 xv = *(const float4*)
        &sX[p][(bh << 8) + ((ln >> 2) << 4) + ((ln & 3) << 2)];

    // ---- Ws[n][k]: 8-lane DPP reduce, split across wave halves ----
    {
      const bool hi = tid >= 256;   // waves 4-7 reduce the k=8..15 half
      float pr[8];
      if (!hi) {
        pr[0]=wa0.x+wb0.x; pr[1]=wa0.y+wb0.y; pr[2]=wa0.z+wb0.z; pr[3]=wa0.w+wb0.w;
        pr[4]=wa1.x+wb1.x; pr[5]=wa1.y+wb1.y; pr[6]=wa1.z+wb1.z; pr[7]=wa1.w+wb1.w;
      } else {
        pr[0]=wa2.x+wb2.x; pr[1]=wa2.y+wb2.y; pr[2]=wa2.z+wb2.z; pr[3]=wa2.w+wb2.w;
        pr[4]=wa3.x+wb3.x; pr[5]=wa3.y+wb3.y; pr[6]=wa3.z+wb3.z; pr[7]=wa3.w+wb3.w;
      }
      #pragma unroll
      for (int q = 0; q < 8; ++q) {
        float v = pr[q];
        v = dpp_addf<DPP_XOR1>(v);
        v = dpp_addf<DPP_XOR2>(v);
        v = dpp_addf<DPP_HALF_MIR>(v);
        pr[q] = v;
      }
      const int m7 = tid & 7;
      const int mb = hi ? 2 : 0;    // this half writes m = mb, mb+1
      if (m7 == mb || m7 == mb + 1) {
        const float4 w = (m7 == mb)
            ? make_float4(pr[0], pr[1], pr[2], pr[3])
            : make_float4(pr[4], pr[5], pr[6], pr[7]);
        *(float4*)&sWs[(t256 >> 3) * 20 + (m7 << 2)] = w;
      }
    }

    lds_barrier();                  // #1: frag/xv reads + sWs writes done ->
                                    // sW free, sWs ready (vmcnt untouched)

    if (ii < 3) {                   // stage next i: full-iteration distance
      stage_x(X + ((size_t)(i0 + ii + 1) << 4), sX[p ^ 1], tid);
      stage_tile(Wt + ((size_t)(i0 + ii + 1) << 13), sW, wv, ln);
    }                               // async; drained at next loop-top sync

    // ---- phase B: x from LDS (broadcast) -> 2-round softmax -> sC ----
    {
      const float* xr = &sX[p][bB << 4];
      const float4 x0 = *(const float4*)(xr + 0);
      const float4 x1 = *(const float4*)(xr + 4);
      const float4 x2 = *(const float4*)(xr + 8);
      const float4 x3 = *(const float4*)(xr + 12);
      float t1 = 0.f, t2 = 0.f;
      #pragma unroll
      for (int c4 = 0; c4 < 4; ++c4) {
        const float4 A1 = *(const float4*)&sWs[n1 * 20 + (c4 << 2)];
        const float4 A2 = *(const float4*)&sWs[(n1 + 16) * 20 + (c4 << 2)];
        const float4 xc = (c4 == 0) ? x0 : (c4 == 1) ? x1 : (c4 == 2) ? x2 : x3;
        t1 += A1.x * xc.x + A1.y * xc.y + A1.z * xc.z + A1.w * xc.w;
        t2 += A2.x * xc.x + A2.y * xc.y + A2.z * xc.z + A2.w * xc.w;
      }
      const float l1a = t1 * 0.03125f, l1b = t2 * 0.03125f;   // b1 = t/32
      const float e1a = exp2f(l1a * LOG2E), e1b = exp2f(l1b * LOG2E);
      float s1 = e1a + e1b;
      s1 = dpp_addf<DPP_XOR1>(s1); s1 = dpp_addf<DPP_XOR2>(s1);
      s1 = dpp_addf<DPP_HALF_MIR>(s1); s1 = dpp_addf<DPP_ROW_MIR>(s1);
      const float rs1 = __builtin_amdgcn_rcpf(s1);
      const float l2a = l1a + e1a * rs1 * t1;                 // b2 = b1 + c1*t
      const float l2b = l1b + e1b * rs1 * t2;
      const float e2a = exp2f(l2a * LOG2E), e2b = exp2f(l2b * LOG2E);
      float s2 = e2a + e2b;
      s2 = dpp_addf<DPP_XOR1>(s2); s2 = dpp_addf<DPP_XOR2>(s2);
      s2 = dpp_addf<DPP_HALF_MIR>(s2); s2 = dpp_addf<DPP_ROW_MIR>(s2);
      const float rs2 = __builtin_amdgcn_rcpf(s2);
      sC[n1 * 36 + bB]        = e2a * rs2;
      sC[(n1 + 16) * 36 + bB] = e2b * rs2;
    }

    // ---- u-hoist: steps 0..7 (frags x readlane-x; independent of sC) ----
    float us0[8], us1[8];
    #pragma unroll
    for (int st = 0; st < 8; ++st) {
      if ((st & 3) == 0) __builtin_amdgcn_sched_barrier(0);  // 4-step window
      const int lb = st << 2;                 // lanes lb..lb+3 hold b=bh*16+st
      const float s00 = rlane(xv.x, lb + 0), s01 = rlane(xv.y, lb + 0),
                  s02 = rlane(xv.z, lb + 0), s03 = rlane(xv.w, lb + 0);
      const float s10 = rlane(xv.x, lb + 1), s11 = rlane(xv.y, lb + 1),
                  s12 = rlane(xv.z, lb + 1), s13 = rlane(xv.w, lb + 1);
      const float s20 = rlane(xv.x, lb + 2), s21 = rlane(xv.y, lb + 2),
                  s22 = rlane(xv.z, lb + 2), s23 = rlane(xv.w, lb + 2);
      const float s30 = rlane(xv.x, lb + 3), s31 = rlane(xv.y, lb + 3),
                  s32 = rlane(xv.z, lb + 3), s33 = rlane(xv.w, lb + 3);
      us0[st] = wa0.x*s00 + wa0.y*s01 + wa0.z*s02 + wa0.w*s03
              + wa1.x*s10 + wa1.y*s11 + wa1.z*s12 + wa1.w*s13
              + wa2.x*s20 + wa2.y*s21 + wa2.z*s22 + wa2.w*s23
              + wa3.x*s30 + wa3.y*s31 + wa3.z*s32 + wa3.w*s33;
      us1[st] = wb0.x*s00 + wb0.y*s01 + wb0.z*s02 + wb0.w*s03
              + wb1.x*s10 + wb1.y*s11 + wb1.z*s12 + wb1.w*s13
              + wb2.x*s20 + wb2.y*s21 + wb2.z*s22 + wb2.w*s23
              + wb3.x*s30 + wb3.y*s31 + wb3.z*s32 + wb3.w*s33;
    }

    lds_barrier();                            // #2: sC ready (vmcnt untouched)

    // ---- pass 2 epilog: c2 weights; fold hoisted steps; finish 8..15 ----
    float c2s[16];
    {
      const int cb = nr * 36 + (bh << 4);
      *(float4*)&c2s[0]  = *(const float4*)&sC[cb + 0];
      *(float4*)&c2s[4]  = *(const float4*)&sC[cb + 4];
      *(float4*)&c2s[8]  = *(const float4*)&sC[cb + 8];
      *(float4*)&c2s[12] = *(const float4*)&sC[cb + 12];
    }
    #pragma unroll
    for (int st = 0; st < 8; ++st) {
      acc0[st] += c2s[st] * us0[st];
      acc1[st] += c2s[st] * us1[st];
    }
    #pragma unroll
    for (int st = 8; st < 16; ++st) {
      if ((st & 3) == 0) __builtin_amdgcn_sched_barrier(0);  // 4-step window
      const int lb = st << 2;
      const float s00 = rlane(xv.x, lb + 0), s01 = rlane(xv.y, lb + 0),
                  s02 = rlane(xv.z, lb + 0), s03 = rlane(xv.w, lb + 0);
      const float s10 = rlane(xv.x, lb + 1), s11 = rlane(xv.y, lb + 1),
                  s12 = rlane(xv.z, lb + 1), s13 = rlane(xv.w, lb + 1);
      const float s20 = rlane(xv.x, lb + 2), s21 = rlane(xv.y, lb + 2),
                  s22 = rlane(xv.z, lb + 2), s23 = rlane(xv.w, lb + 2);
      const float s30 = rlane(xv.x, lb + 3), s31 = rlane(xv.y, lb + 3),
                  s32 = rlane(xv.z, lb + 3), s33 = rlane(xv.w, lb + 3);
      float u0 = wa0.x*s00 + wa0.y*s01 + wa0.z*s02 + wa0.w*s03
               + wa1.x*s10 + wa1.y*s11 + wa1.z*s12 + wa1.w*s13
               + wa2.x*s20 + wa2.y*s21 + wa2.z*s22 + wa2.w*s23
               + wa3.x*s30 + wa3.y*s31 + wa3.z*s32 + wa3.w*s33;
      float u1 = wb0.x*s00 + wb0.y*s01 + wb0.z*s02 + wb0.w*s03
               + wb1.x*s10 + wb1.y*s11 + wb1.z*s12 + wb1.w*s13
               + wb2.x*s20 + wb2.y*s21 + wb2.z*s22 + wb2.w*s23
               + wb3.x*s30 + wb3.y*s31 + wb3.z*s32 + wb3.w*s33;
      acc0[st] += c2s[st] * u0;
      acc1[st] += c2s[st] * u1;
    }
  }

  if constexpr (ATOMIC) {
    #pragma unroll
    for (int j = 0; j < 16; ++j) {
      const int bgl = (bh << 4) + j;
      float* dst = part + ((size_t)bgl << 9) + (t256 << 1);
      atomicAdd(dst, acc0[j]);
      atomicAdd(dst + 1, acc1[j]);
    }
  } else {
    float* wp = part + ((size_t)blockIdx.x << 14) + (t256 << 1);
    #pragma unroll
    for (int j = 0; j < 16; ++j) {
      const int bgl = (bh << 4) + j;
      *(float2*)(wp + ((size_t)bgl << 9)) = make_float2(acc0[j], acc1[j]);
    }
  }
}

// K2: reduce 512 partials + squash. grid 256 (b = bid>>3, r-block = bid&7).
__global__ __launch_bounds__(512)
void caps_reduce(const float* __restrict__ part, float* __restrict__ out) {
  __shared__ float sred[32][64];
  const int tid = threadIdx.x;
  const int bid = blockIdx.x;            // 0..255
  const int b  = bid >> 3;               // 0..31
  const int rb = bid & 7;                // 64-elem row block
  const int pg = tid >> 4;               // 0..31: sums ig in [16pg, 16pg+16)
  const int sl = tid & 15;               // float4 slot
  const float* src = part + (((size_t)pg << 4) << 14)
                   + (b << 9) + (rb << 6) + (sl << 2);
  float4 a = make_float4(0.f, 0.f, 0.f, 0.f);
  #pragma unroll 4
  for (int p = 0; p < 16; ++p) {
    const float4 v = *(const float4*)(src + ((size_t)p << 14));
    a.x += v.x; a.y += v.y; a.z += v.z; a.w += v.w;
  }
  *(float4*)&sred[pg][sl << 2] = a;
  __syncthreads();
  if (tid < 64) {
    float s = 0.f;
    #pragma unroll
    for (int g = 0; g < 32; ++g) s += sred[g][tid];
    float sq = s * s;
    sq += __shfl_xor(sq, 1); sq += __shfl_xor(sq, 2);
    sq += __shfl_xor(sq, 4); sq += __shfl_xor(sq, 8);   // sum over d (16 r's)
    const float scale = sq / (1.0f + sq) / sqrtf(sq + 1e-7f);
    out[(b << 9) + (rb << 6) + tid] = scale * s;
  }
}

// fallback path: squash fully-accumulated sums
__global__ __launch_bounds__(256)
void caps_squash(const float* __restrict__ sums, float* __restrict__ out) {
  const int e = (blockIdx.x << 8) + threadIdx.x;
  const float s = sums[e];
  float sq = s * s;
  sq += __shfl_xor(sq, 1); sq += __shfl_xor(sq, 2);
  sq += __shfl_xor(sq, 4); sq += __shfl_xor(sq, 8);
  const float scale = sq / (1.0f + sq) / sqrtf(sq + 1e-7f);
  out[e] = scale * s;
}

extern "C" void kernel_launch(void* const* d_in, const int* in_sizes, int n_in,
                              void* d_out, int out_size, void* d_ws, size_t ws_size,
                              hipStream_t stream) {
  const float* X  = (const float*)d_in[0];
  const float* Wt = (const float*)d_in[1];
  float* out = (float*)d_out;
  float* wsf = (float*)d_ws;
  const size_t need = (size_t)512 * 16384 * sizeof(float);
  if (ws_size >= need) {
    caps_main<false><<<512, 512, 0, stream>>>(X, Wt, wsf);
    caps_reduce<<<256, 512, 0, stream>>>(wsf, out);
  } else {
    float* acc = (ws_size >= (size_t)16384 * sizeof(float)) ? wsf : out;
    hipMemsetAsync(acc, 0, 16384 * sizeof(float), stream);
    caps_main<true><<<512, 512, 0, stream>>>(X, Wt, acc);
    caps_squash<<<64, 256, 0, stream>>>(acc, out);
  }
}